// Round 11
// baseline (194.465 us; speedup 1.0000x reference)
//
#include <hip/hip_runtime.h>
#include <hip/hip_bf16.h>
#include <stdint.h>
#include <math.h>

#define RES     256
#define M_MEAS  8192
#define KDIM    8192
#define ROWSC   2048        // 4 batches * {Re 0..255, Im 256..511}
#define NCOLS   288         // cos u at [0,129)+pad, sin u at [144,273)+pad
#define SINOFF  144
#define SPLIT   16
#define KCHUNK  512
#define BM      128
#define BN      144
#define BK      64
#define NT      (KCHUNK / BK)   // 8
#define TWO_PI  6.28318530717958647692f
#define NBLK    512

typedef __attribute__((ext_vector_type(8))) __bf16 bf16x8;
typedef __attribute__((ext_vector_type(8))) unsigned short u16x8;
typedef __attribute__((ext_vector_type(4))) float f32x4;
typedef __attribute__((ext_vector_type(2))) float f32x2;

// ---- workspace layout (bytes) ----
#define OFF_SRE 0
#define OFF_SIM 131072
#define OFF_KY  262144
#define OFF_B   294912          // Bt bf16[288][8192]
#define OFF_C   5013504         // Cp bf16[16][2048][288]
#define OFF_BAR 23887872        // 2 barriers x {cnt,flag} u32 = 16 B (memset to 0 each launch)

__device__ __forceinline__ unsigned short f2bf(float f) {
    unsigned u = __float_as_uint(f);
    u += 0x7FFFu + ((u >> 16) & 1u);          // round-to-nearest-even
    return (unsigned short)(u >> 16);
}

__device__ __forceinline__ float bf2f(unsigned short v) {
    unsigned u = ((unsigned)v) << 16;
    return __uint_as_float(u);
}

__device__ __forceinline__ void lds_load16(const void* g, void* l) {
    __builtin_amdgcn_global_load_lds(
        (const __attribute__((address_space(1))) uint32_t*)(uintptr_t)g,
        (__attribute__((address_space(3))) uint32_t*)(uint32_t)(uintptr_t)l,
        16, 0, 0);
}

// Replay-safe grid barrier: bar = {count, flag}, zeroed by hipMemsetAsync per launch.
__device__ __forceinline__ void grid_barrier(unsigned* bar) {
    __syncthreads();
    if (threadIdx.x == 0) {
        __threadfence();                                       // release my writes
        unsigned t = __hip_atomic_fetch_add(&bar[0], 1u, __ATOMIC_ACQ_REL,
                                            __HIP_MEMORY_SCOPE_AGENT);
        if (t == NBLK - 1u) {
            __hip_atomic_store(&bar[1], 1u, __ATOMIC_RELEASE,
                               __HIP_MEMORY_SCOPE_AGENT);
        } else {
            unsigned spins = 0;
            while (__hip_atomic_load(&bar[1], __ATOMIC_ACQUIRE,
                                     __HIP_MEMORY_SCOPE_AGENT) == 0u) {
                __builtin_amdgcn_s_sleep(8);
                if (++spins > 100000000u) break;               // failsafe vs hang
            }
        }
        __threadfence();                                       // acquire others' writes
    }
    __syncthreads();
}

// ================= single fused kernel: prep | gemm | combine =================
__global__ __launch_bounds__(256, 2) void k_fused(const float* __restrict__ in,
                                                  const float* __restrict__ xs,
                                                  float* __restrict__ sRe,
                                                  float* __restrict__ sIm,
                                                  float* __restrict__ kyc,
                                                  unsigned short* __restrict__ Bt,
                                                  unsigned short* __restrict__ Cp,
                                                  unsigned* __restrict__ bars,
                                                  float* __restrict__ out) {
    __shared__ __align__(16) char arena[77824];                // 76 KB (2 blocks/CU)
    unsigned short (*As)[BM * BK] = (unsigned short (*)[BM * BK])arena;            // 2x16KB
    unsigned short (*Bs)[BN * BK] = (unsigned short (*)[BN * BK])(arena + 32768);  // 2x18KB
    float* sbuf = (float*)(arena + 69632);                     // 2048 floats (8 KB)
    float* part = (float*)arena;                               // phase C alias

    int tid = threadIdx.x;

    // ================= PHASE A: gather s + ky, build Bt (r9 prep, strided) ==========
    for (int vb = blockIdx.x; vb < 1280; vb += NBLK) {
        if (vb < 128) {
            int t = vb * 256 + tid;                   // 32768
            int b = t >> 13, m = t & (M_MEAS - 1);
            float kx = xs[2 * m + 0], ky = xs[2 * m + 1];
            if (t < M_MEAS) kyc[t] = xs[2 * t + 1];
            float gx = (kx * (1.0f / 128.0f) + 1.0f) * 0.5f * 255.0f;
            float gy = (ky * (1.0f / 128.0f) + 1.0f) * 0.5f * 255.0f;
            float fx0 = floorf(gx), fy0 = floorf(gy);
            float wx1 = gx - fx0, wx0 = 1.0f - wx1;
            float wy1 = gy - fy0, wy0 = 1.0f - wy1;
            int x0 = (int)fx0, y0 = (int)fy0;
            float re = 0.0f, im = 0.0f;
#pragma unroll
            for (int dy = 0; dy < 2; ++dy) {
#pragma unroll
                for (int dx = 0; dx < 2; ++dx) {
                    int xi = x0 + dx, yi = y0 + dy;
                    bool v = (xi >= 0) && (xi < RES) && (yi >= 0) && (yi < RES);
                    int xc = min(max(xi, 0), RES - 1);
                    int yc = min(max(yi, 0), RES - 1);
                    float w = (dx ? wx1 : wx0) * (dy ? wy1 : wy0) * (v ? 1.0f : 0.0f);
                    const float* p = in + ((((size_t)b * RES + yc) * RES + xc) * 2);
                    re += p[0] * w;
                    im += p[1] * w;
                }
            }
            sRe[b * M_MEAS + m] = re;
            sIm[b * M_MEAS + m] = im;
        } else {
            int t = (vb - 128) * 256 + tid;           // 294912 = 288*1024
            int cidx = t >> 10;
            int m0 = (t & 1023) * 8;
            bool isCos = cidx < SINOFF;
            int u = isCos ? cidx : (cidx - SINOFF);
            u16x8 v;
            if (u > 128) {
                v = (u16x8){0, 0, 0, 0, 0, 0, 0, 0};
            } else {
                float nn = (float)u;
#pragma unroll
                for (int j = 0; j < 8; ++j) {
                    float kx = xs[2 * (m0 + j) + 0];
                    float ur = kx * nn * (1.0f / 256.0f);
                    ur -= rintf(ur);
                    float th = ur * TWO_PI;
                    v[j] = f2bf(isCos ? __cosf(th) : __sinf(th));
                }
            }
            *(u16x8*)(Bt + (size_t)cidx * KDIM + m0) = v;
        }
    }

    grid_barrier(bars);                                // A -> B

    // ================= PHASE B: split-K GEMM, on-the-fly A (r9 exact) ===============
    {
        int bid = blockIdx.x;              // 512 = 2 col * 16 row * 16 split
        int tc = bid & 1, rest = bid >> 1;
        int tr = rest & 15, split = rest >> 4;
        int col0 = tc * BN;
        int kbase = split * KCHUNK;
        int yhalf = tr & 1, isIm = (tr >> 1) & 1, batch = tr >> 2;
        int w = tid >> 6, l = tid & 63;
        int lr = l & 15, lu = l >> 4;

        f32x4 acc[2][9] = {};

#define STAGE_B(buf, kt)                                                          \
    do {                                                                          \
        _Pragma("unroll")                                                         \
        for (int q = 0; q < 5; ++q) {                                             \
            int U = q * 256 + tid; if (U >= 1152) U -= 1152;                      \
            int r = U >> 3, u = U & 7;                                            \
            lds_load16(Bt + (size_t)(col0 + r) * KDIM + kbase + (kt) * BK         \
                          + ((u ^ (r & 7)) * 8),                                  \
                       &Bs[buf][U * 8]);                                          \
        }                                                                         \
    } while (0)

#define GEN_A(buf, kt)                                                            \
    do {                                                                          \
        int p = tid & 31, g = tid >> 5;                                           \
        int mi = (kt) * BK + p * 2;                                               \
        float2 kyp = *(const float2*)&sbuf[mi];                                   \
        float2 srp = *(const float2*)&sbuf[KCHUNK + mi];                          \
        float2 sip = *(const float2*)&sbuf[2 * KCHUNK + mi];                      \
        float n0 = (float)(yhalf * 128 + g * 16 - 128);                           \
        float c0, s0, c1, s1, cs0, ss0, cs1, ss1;                                 \
        { float u = kyp.x * n0 * (1.0f/256.0f); u -= rintf(u);                    \
          s0 = __sinf(u * TWO_PI); c0 = __cosf(u * TWO_PI); }                     \
        { float u = kyp.x * (1.0f/256.0f); u -= rintf(u);                         \
          ss0 = __sinf(u * TWO_PI); cs0 = __cosf(u * TWO_PI); }                   \
        { float u = kyp.y * n0 * (1.0f/256.0f); u -= rintf(u);                    \
          s1 = __sinf(u * TWO_PI); c1 = __cosf(u * TWO_PI); }                     \
        { float u = kyp.y * (1.0f/256.0f); u -= rintf(u);                         \
          ss1 = __sinf(u * TWO_PI); cs1 = __cosf(u * TWO_PI); }                   \
        _Pragma("unroll")                                                         \
        for (int j = 0; j < 16; ++j) {                                            \
            int r = g * 16 + j;                                                   \
            float v0 = isIm ? fmaf(srp.x, s0, sip.x * c0)                         \
                            : fmaf(srp.x, c0, -(sip.x * s0));                     \
            float v1 = isIm ? fmaf(srp.y, s1, sip.y * c1)                         \
                            : fmaf(srp.y, c1, -(sip.y * s1));                     \
            unsigned pk = (unsigned)f2bf(v0) | ((unsigned)f2bf(v1) << 16);        \
            *(unsigned*)&As[buf][r * 64 + (((p >> 2) ^ (r & 7)) * 8) + (p & 3) * 2] = pk; \
            float nc0 = fmaf(c0, cs0, -(s0 * ss0));                               \
            float ns0 = fmaf(s0, cs0,  (c0 * ss0));                               \
            c0 = nc0; s0 = ns0;                                                   \
            float nc1 = fmaf(c1, cs1, -(s1 * ss1));                               \
            float ns1 = fmaf(s1, cs1,  (c1 * ss1));                               \
            c1 = nc1; s1 = ns1;                                                   \
        }                                                                         \
    } while (0)

#pragma unroll
        for (int q = 0; q < 2; ++q) {
            int V = q * 256 + tid; if (V >= 384) V -= 384;
            int rg = V >> 7, idx = V & 127;
            const float* s = (rg == 0) ? kyc
                           : (rg == 1) ? (sRe + (size_t)batch * M_MEAS)
                                       : (sIm + (size_t)batch * M_MEAS);
            lds_load16(s + kbase + idx * 4, &sbuf[V * 4]);
        }
        STAGE_B(0, 0);
        asm volatile("s_waitcnt vmcnt(5)" ::: "memory");
        __builtin_amdgcn_s_barrier();
        GEN_A(0, 0);
        asm volatile("s_waitcnt vmcnt(0) lgkmcnt(0)" ::: "memory");
        __builtin_amdgcn_sched_barrier(0);
        __builtin_amdgcn_s_barrier();

        for (int t = 0; t < NT; ++t) {
            int cur = t & 1;
            if (t < NT - 1) {
                STAGE_B(cur ^ 1, t + 1);
                GEN_A(cur ^ 1, t + 1);
            }

            bf16x8 af[2][2], bfr[2][9];
#pragma unroll
            for (int ks = 0; ks < 2; ++ks) {
                int uu = ks * 4 + lu;
#pragma unroll
                for (int i = 0; i < 2; ++i) {
                    int r = w * 32 + i * 16 + lr;
                    af[ks][i] = *(const bf16x8*)&As[cur][r * 64 + ((uu ^ (r & 7)) * 8)];
                }
#pragma unroll
                for (int j = 0; j < 9; ++j) {
                    int r = j * 16 + lr;
                    bfr[ks][j] = *(const bf16x8*)&Bs[cur][r * 64 + ((uu ^ (r & 7)) * 8)];
                }
            }
            asm volatile("s_waitcnt lgkmcnt(0)" ::: "memory");
            __builtin_amdgcn_sched_barrier(0);
            __builtin_amdgcn_s_setprio(1);
#pragma unroll
            for (int ks = 0; ks < 2; ++ks)
#pragma unroll
                for (int i = 0; i < 2; ++i)
#pragma unroll
                    for (int j = 0; j < 9; ++j)
                        acc[i][j] = __builtin_amdgcn_mfma_f32_16x16x32_bf16(af[ks][i], bfr[ks][j], acc[i][j], 0, 0, 0);
            __builtin_amdgcn_s_setprio(0);
            asm volatile("s_waitcnt vmcnt(0)" ::: "memory");
            __builtin_amdgcn_sched_barrier(0);
            __builtin_amdgcn_s_barrier();
        }
#undef STAGE_B
#undef GEN_A

        unsigned short* Cb = Cp + (size_t)split * ROWSC * NCOLS;
#pragma unroll
        for (int i = 0; i < 2; ++i) {
#pragma unroll
            for (int j = 0; j < 9; ++j) {
                int colg = col0 + j * 16 + lr;
#pragma unroll
                for (int v = 0; v < 4; ++v) {
                    int rowg = tr * BM + w * 32 + i * 16 + lu * 4 + v;
                    Cb[(size_t)rowg * NCOLS + colg] = f2bf(acc[i][j][v]);
                }
            }
        }
    }

    grid_barrier(bars + 2);                            // B -> C

    // ================= PHASE C: split-K reduce + symmetry (r9 combine, x2) ==========
    for (int vb = blockIdx.x; vb < 1024; vb += NBLK) {
        int b = vb >> 8, y = vb & 255;
        int q = tid >> 6, un = tid & 63;

        size_t rRe = ((size_t)b * 512 + y) * NCOLS;
        size_t rIm = rRe + (size_t)256 * NCOLS;

#pragma unroll
        for (int rep = 0; rep < 2; ++rep) {
            int unit = un + rep * 64;
            if (rep == 1 && un >= 4) break;
            int seg = unit / 17, uidx = unit - seg * 17;
            size_t base = ((seg & 2) ? rIm : rRe) + ((seg & 1) ? SINOFF : 0) + uidx * 8;
            float a[8] = {};
#pragma unroll
            for (int s2 = 0; s2 < 4; ++s2) {
                const unsigned short* Cb = Cp + (size_t)(q * 4 + s2) * ROWSC * NCOLS;
                u16x8 v = *(const u16x8*)(Cb + base);
#pragma unroll
                for (int k = 0; k < 8; ++k) a[k] += bf2f(v[k]);
            }
#pragma unroll
            for (int k = 0; k < 8; ++k) part[(q * 68 + unit) * 9 + k] = a[k];
        }
        __syncthreads();

        if (tid < 68) {
#pragma unroll
            for (int k = 0; k < 8; ++k) {
                float s = part[(0 * 68 + tid) * 9 + k] + part[(1 * 68 + tid) * 9 + k]
                        + part[(2 * 68 + tid) * 9 + k] + part[(3 * 68 + tid) * 9 + k];
                part[tid * 9 + k] = s;
            }
        }
        __syncthreads();

        int x = tid;
        int n = x - 128;
        int u = (n < 0) ? -n : n;
        float sg = (n < 0) ? -1.0f : 1.0f;
        int ui = u >> 3, uk = u & 7;
        float cr = part[(0 * 17 + ui) * 9 + uk];
        float sr = part[(17 + ui) * 9 + uk];
        float ci = part[(34 + ui) * 9 + uk];
        float si = part[(51 + ui) * 9 + uk];
        float re = cr - sg * si;
        float im = sg * sr + ci;
        ((f32x2*)out)[(size_t)(b * 256 + y) * 256 + x] = (f32x2){re, im};
        __syncthreads();                               // protect part[] reuse next iter
    }
}

extern "C" void kernel_launch(void* const* d_in, const int* in_sizes, int n_in,
                              void* d_out, int out_size, void* d_ws, size_t ws_size,
                              hipStream_t stream) {
    const float* in = (const float*)d_in[0];
    const float* xs = (const float*)d_in[1];
    float* out = (float*)d_out;
    char* ws = (char*)d_ws;

    float* sRe = (float*)(ws + OFF_SRE);
    float* sIm = (float*)(ws + OFF_SIM);
    float* kyc = (float*)(ws + OFF_KY);
    unsigned short* Bt = (unsigned short*)(ws + OFF_B);
    unsigned short* Cp = (unsigned short*)(ws + OFF_C);
    unsigned* bars = (unsigned*)(ws + OFF_BAR);

    hipMemsetAsync(bars, 0, 16, stream);               // replay-safe barrier reset
    k_fused<<<NBLK, 256, 0, stream>>>(in, xs, sRe, sIm, kyc, Bt, Cp, bars, out);
}

// Round 13
// 44.858 us; speedup vs baseline: 4.3351x; 4.3351x over previous
//
#include <hip/hip_runtime.h>
#include <hip/hip_bf16.h>
#include <stdint.h>
#include <math.h>

#define RES     256
#define M_MEAS  8192
#define KDIM    8192
#define ROWSC   2048        // 4 batches * {Re 0..255, Im 256..511}
#define NCOLS   288         // cos u at [0,129)+pad cols 0..143, sin at 144..287
#define SINOFF  144
#define SPLIT   16
#define KCHUNK  512
#define BM      128
#define BN      144
#define BK      64
#define NT      (KCHUNK / BK)   // 8
#define TWO_PI  6.28318530717958647692f

typedef __attribute__((ext_vector_type(8))) __bf16 bf16x8;
typedef __attribute__((ext_vector_type(8))) unsigned short u16x8;
typedef __attribute__((ext_vector_type(4))) float f32x4;
typedef __attribute__((ext_vector_type(2))) float f32x2;

// ---- workspace: Cp bf16[16][2048][288] @0 (18.9 MB) ----

__device__ __forceinline__ unsigned short f2bf(float f) {
    unsigned u = __float_as_uint(f);
    u += 0x7FFFu + ((u >> 16) & 1u);          // round-to-nearest-even
    return (unsigned short)(u >> 16);
}

__device__ __forceinline__ float bf2f(unsigned short v) {
    unsigned u = ((unsigned)v) << 16;
    return __uint_as_float(u);
}

// sbuf layout (floats)
#define SB_KX 0
#define SB_KY 512
#define SB_RE 1024
#define SB_IM 1536

// ---------------- kernel 1: fully-fused split-K GEMM ---------------------------------
// Per block: gather its own s samples, generate A (s*Ey) AND B (Ex trig) tiles on the
// fly in LDS. No global staging in the K-loop; one barrier per K-step.
__global__ __launch_bounds__(256, 2) void k_gemm(const float* __restrict__ in,
                                                 const float* __restrict__ xs,
                                                 unsigned short* __restrict__ Cp) {
    __shared__ __align__(16) unsigned short As[2][BM * BK];   // 2 x 16 KB
    __shared__ __align__(16) unsigned short Bs[2][BN * BK];   // 2 x 18 KB
    __shared__ __align__(16) float sbuf[4 * 512];             // kx|ky|sRe|sIm, 8 KB

    int bid = blockIdx.x;              // 512 = 2 col * 16 row * 16 split
    int tc = bid & 1, rest = bid >> 1;
    int tr = rest & 15, split = rest >> 4;
    int col0 = tc * BN;
    int kbase = split * KCHUNK;
    int yhalf = tr & 1, isIm = (tr >> 1) & 1, batch = tr >> 2;
    int tid = threadIdx.x;
    int w = tid >> 6, l = tid & 63;
    int lr = l & 15, lu = l >> 4;

    f32x4 acc[2][9] = {};

    // ---- prologue: load kx/ky + gather s for this (batch, kchunk) into sbuf ----
    {
        int i0 = tid * 2;                          // 0..510
        int m = kbase + i0;
        f32x4 xv = *(const f32x4*)(xs + 2 * m);    // kx0,ky0,kx1,ky1 (16B aligned)
        sbuf[SB_KX + i0]     = xv.x;
        sbuf[SB_KY + i0]     = xv.y;
        sbuf[SB_KX + i0 + 1] = xv.z;
        sbuf[SB_KY + i0 + 1] = xv.w;
        const float* img = in + (size_t)batch * RES * RES * 2;
#pragma unroll
        for (int e = 0; e < 2; ++e) {
            float kx = e ? xv.z : xv.x;
            float ky = e ? xv.w : xv.y;
            float gx = (kx * (1.0f / 128.0f) + 1.0f) * 0.5f * 255.0f;
            float gy = (ky * (1.0f / 128.0f) + 1.0f) * 0.5f * 255.0f;
            float fx0 = floorf(gx), fy0 = floorf(gy);
            float wx1 = gx - fx0, wx0 = 1.0f - wx1;
            float wy1 = gy - fy0, wy0 = 1.0f - wy1;
            int x0 = (int)fx0, y0 = (int)fy0;
            float re = 0.0f, im = 0.0f;
#pragma unroll
            for (int dy = 0; dy < 2; ++dy) {
#pragma unroll
                for (int dx = 0; dx < 2; ++dx) {
                    int xi = x0 + dx, yi = y0 + dy;
                    bool v = (xi >= 0) && (xi < RES) && (yi >= 0) && (yi < RES);
                    int xc = min(max(xi, 0), RES - 1);
                    int yc = min(max(yi, 0), RES - 1);
                    float wt = (dx ? wx1 : wx0) * (dy ? wy1 : wy0) * (v ? 1.0f : 0.0f);
                    const float* p = img + (((size_t)yc * RES + xc) * 2);
                    re += p[0] * wt;
                    im += p[1] * wt;
                }
            }
            sbuf[SB_RE + i0 + e] = re;
            sbuf[SB_IM + i0 + e] = im;
        }
    }
    __syncthreads();                               // sbuf complete

    // ---- A generation: lane owns m-pair p, 16 y-rows; sincos once + rotations ----
#define GEN_A(buf, kt)                                                            \
    do {                                                                          \
        int p = tid & 31, g = tid >> 5;                                           \
        int mi = (kt) * BK + p * 2;                                               \
        float2 kyp = *(const float2*)&sbuf[SB_KY + mi];                           \
        float2 srp = *(const float2*)&sbuf[SB_RE + mi];                           \
        float2 sip = *(const float2*)&sbuf[SB_IM + mi];                           \
        float n0 = (float)(yhalf * 128 + g * 16 - 128);                           \
        float c0, s0, c1, s1, cs0, ss0, cs1, ss1;                                 \
        { float u = kyp.x * n0 * (1.0f/256.0f); u -= rintf(u);                    \
          s0 = __sinf(u * TWO_PI); c0 = __cosf(u * TWO_PI); }                     \
        { float u = kyp.x * (1.0f/256.0f); u -= rintf(u);                         \
          ss0 = __sinf(u * TWO_PI); cs0 = __cosf(u * TWO_PI); }                   \
        { float u = kyp.y * n0 * (1.0f/256.0f); u -= rintf(u);                    \
          s1 = __sinf(u * TWO_PI); c1 = __cosf(u * TWO_PI); }                     \
        { float u = kyp.y * (1.0f/256.0f); u -= rintf(u);                         \
          ss1 = __sinf(u * TWO_PI); cs1 = __cosf(u * TWO_PI); }                   \
        _Pragma("unroll")                                                         \
        for (int j = 0; j < 16; ++j) {                                            \
            int r = g * 16 + j;                                                   \
            float v0 = isIm ? fmaf(srp.x, s0, sip.x * c0)                         \
                            : fmaf(srp.x, c0, -(sip.x * s0));                     \
            float v1 = isIm ? fmaf(srp.y, s1, sip.y * c1)                         \
                            : fmaf(srp.y, c1, -(sip.y * s1));                     \
            unsigned pk = (unsigned)f2bf(v0) | ((unsigned)f2bf(v1) << 16);        \
            *(unsigned*)&As[buf][r * 64 + (((p >> 2) ^ (r & 7)) * 8) + (p & 3) * 2] = pk; \
            float nc0 = fmaf(c0, cs0, -(s0 * ss0));                               \
            float ns0 = fmaf(s0, cs0,  (c0 * ss0));                               \
            c0 = nc0; s0 = ns0;                                                   \
            float nc1 = fmaf(c1, cs1, -(s1 * ss1));                               \
            float ns1 = fmaf(s1, cs1,  (c1 * ss1));                               \
            c1 = nc1; s1 = ns1;                                                   \
        }                                                                         \
    } while (0)

    // ---- B generation: lane owns m-pair p, 18 u-rows; value = cos or sin(2pi kx u/256)
#define GEN_B(buf, kt)                                                            \
    do {                                                                          \
        int p = tid & 31, g = tid >> 5;                                           \
        int mi = (kt) * BK + p * 2;                                               \
        float2 kxp = *(const float2*)&sbuf[SB_KX + mi];                           \
        float r0 = (float)(g * 18);                                               \
        float c0, s0, c1, s1, cs0, ss0, cs1, ss1;                                 \
        { float u = kxp.x * r0 * (1.0f/256.0f); u -= rintf(u);                    \
          s0 = __sinf(u * TWO_PI); c0 = __cosf(u * TWO_PI); }                     \
        { float u = kxp.x * (1.0f/256.0f); u -= rintf(u);                         \
          ss0 = __sinf(u * TWO_PI); cs0 = __cosf(u * TWO_PI); }                   \
        { float u = kxp.y * r0 * (1.0f/256.0f); u -= rintf(u);                    \
          s1 = __sinf(u * TWO_PI); c1 = __cosf(u * TWO_PI); }                     \
        { float u = kxp.y * (1.0f/256.0f); u -= rintf(u);                         \
          ss1 = __sinf(u * TWO_PI); cs1 = __cosf(u * TWO_PI); }                   \
        _Pragma("unroll")                                                         \
        for (int j = 0; j < 18; ++j) {                                            \
            int r = g * 18 + j;                                                   \
            float live = (r <= 128) ? 1.0f : 0.0f;                                \
            float v0 = (tc ? s0 : c0) * live;                                     \
            float v1 = (tc ? s1 : c1) * live;                                     \
            unsigned pk = (unsigned)f2bf(v0) | ((unsigned)f2bf(v1) << 16);        \
            *(unsigned*)&Bs[buf][r * 64 + (((p >> 2) ^ (r & 7)) * 8) + (p & 3) * 2] = pk; \
            float nc0 = fmaf(c0, cs0, -(s0 * ss0));                               \
            float ns0 = fmaf(s0, cs0,  (c0 * ss0));                               \
            c0 = nc0; s0 = ns0;                                                   \
            float nc1 = fmaf(c1, cs1, -(s1 * ss1));                               \
            float ns1 = fmaf(s1, cs1,  (c1 * ss1));                               \
            c1 = nc1; s1 = ns1;                                                   \
        }                                                                         \
    } while (0)

    GEN_B(0, 0);
    GEN_A(0, 0);
    __syncthreads();                               // buf0 ready for all waves

    for (int t = 0; t < NT; ++t) {
        int cur = t & 1;
        if (t < NT - 1) {
            GEN_B(cur ^ 1, t + 1);                 // VALU; overlaps other waves' MFMA
            GEN_A(cur ^ 1, t + 1);
        }

        bf16x8 af[2][2], bfr[2][9];
#pragma unroll
        for (int ks = 0; ks < 2; ++ks) {
            int uu = ks * 4 + lu;
#pragma unroll
            for (int i = 0; i < 2; ++i) {
                int r = w * 32 + i * 16 + lr;
                af[ks][i] = *(const bf16x8*)&As[cur][r * 64 + ((uu ^ (r & 7)) * 8)];
            }
#pragma unroll
            for (int j = 0; j < 9; ++j) {
                int r = j * 16 + lr;
                bfr[ks][j] = *(const bf16x8*)&Bs[cur][r * 64 + ((uu ^ (r & 7)) * 8)];
            }
        }
        asm volatile("s_waitcnt lgkmcnt(0)" ::: "memory");   // reads + own GEN writes done
        __builtin_amdgcn_sched_barrier(0);
        __builtin_amdgcn_s_setprio(1);
#pragma unroll
        for (int ks = 0; ks < 2; ++ks)
#pragma unroll
            for (int i = 0; i < 2; ++i)
#pragma unroll
                for (int j = 0; j < 9; ++j)
                    acc[i][j] = __builtin_amdgcn_mfma_f32_16x16x32_bf16(af[ks][i], bfr[ks][j], acc[i][j], 0, 0, 0);
        __builtin_amdgcn_s_setprio(0);
        __builtin_amdgcn_sched_barrier(0);
        __builtin_amdgcn_s_barrier();              // all waves done with cur
    }
#undef GEN_A
#undef GEN_B

    unsigned short* Cb = Cp + (size_t)split * ROWSC * NCOLS;
#pragma unroll
    for (int i = 0; i < 2; ++i) {
#pragma unroll
        for (int j = 0; j < 9; ++j) {
            int colg = col0 + j * 16 + lr;
#pragma unroll
            for (int v = 0; v < 4; ++v) {
                int rowg = tr * BM + w * 32 + i * 16 + lu * 4 + v;
                Cb[(size_t)rowg * NCOLS + colg] = f2bf(acc[i][j][v]);
            }
        }
    }
}

// ---------------- kernel 2: block-per-(b,y) cooperative split-K reduce (r9 exact) ----
__global__ __launch_bounds__(256) void k_combine(const unsigned short* __restrict__ Cp,
                                                 float* __restrict__ out) {
    __shared__ float part[4 * 68 * 9];            // 9792 B
    int blk = blockIdx.x;
    int b = blk >> 8, y = blk & 255;
    int tid = threadIdx.x;
    int q = tid >> 6, un = tid & 63;

    size_t rRe = ((size_t)b * 512 + y) * NCOLS;
    size_t rIm = rRe + (size_t)256 * NCOLS;

#pragma unroll
    for (int rep = 0; rep < 2; ++rep) {
        int unit = un + rep * 64;
        if (rep == 1 && un >= 4) break;
        int seg = unit / 17, uidx = unit - seg * 17;
        size_t base = ((seg & 2) ? rIm : rRe) + ((seg & 1) ? SINOFF : 0) + uidx * 8;
        float a[8] = {};
#pragma unroll
        for (int s2 = 0; s2 < 4; ++s2) {
            const unsigned short* Cb = Cp + (size_t)(q * 4 + s2) * ROWSC * NCOLS;
            u16x8 v = *(const u16x8*)(Cb + base);
#pragma unroll
            for (int k = 0; k < 8; ++k) a[k] += bf2f(v[k]);
        }
#pragma unroll
        for (int k = 0; k < 8; ++k) part[(q * 68 + unit) * 9 + k] = a[k];
    }
    __syncthreads();

    if (tid < 68) {
#pragma unroll
        for (int k = 0; k < 8; ++k) {
            float s = part[(0 * 68 + tid) * 9 + k] + part[(1 * 68 + tid) * 9 + k]
                    + part[(2 * 68 + tid) * 9 + k] + part[(3 * 68 + tid) * 9 + k];
            part[tid * 9 + k] = s;
        }
    }
    __syncthreads();

    int x = tid;
    int n = x - 128;
    int u = (n < 0) ? -n : n;
    float sg = (n < 0) ? -1.0f : 1.0f;
    int ui = u >> 3, uk = u & 7;
    float cr = part[(0 * 17 + ui) * 9 + uk];
    float sr = part[(17 + ui) * 9 + uk];
    float ci = part[(34 + ui) * 9 + uk];
    float si = part[(51 + ui) * 9 + uk];
    float re = cr - sg * si;
    float im = sg * sr + ci;
    ((f32x2*)out)[(size_t)(b * 256 + y) * 256 + x] = (f32x2){re, im};
}

extern "C" void kernel_launch(void* const* d_in, const int* in_sizes, int n_in,
                              void* d_out, int out_size, void* d_ws, size_t ws_size,
                              hipStream_t stream) {
    const float* in = (const float*)d_in[0];
    const float* xs = (const float*)d_in[1];
    float* out = (float*)d_out;
    unsigned short* Cp = (unsigned short*)d_ws;

    k_gemm   <<<512,  256, 0, stream>>>(in, xs, Cp);
    k_combine<<<1024, 256, 0, stream>>>(Cp, out);
}

// Round 14
// 40.618 us; speedup vs baseline: 4.7876x; 1.1044x over previous
//
#include <hip/hip_runtime.h>
#include <hip/hip_bf16.h>
#include <stdint.h>
#include <math.h>

#define RES     256
#define M_MEAS  8192
#define KDIM    8192
#define ROWSC   2048        // 4 batches * {Re 0..255, Im 256..511}
#define NCOLS   288         // cos u at [0,129)+pad, sin u at [144,273)+pad
#define SINOFF  144
#define SPLIT   16
#define KCHUNK  512
#define BM      128
#define BN      144
#define BK      64
#define NT      (KCHUNK / BK)   // 8
#define TWO_PI  6.28318530717958647692f

typedef __attribute__((ext_vector_type(8))) __bf16 bf16x8;
typedef __attribute__((ext_vector_type(8))) unsigned short u16x8;
typedef __attribute__((ext_vector_type(4))) float f32x4;
typedef __attribute__((ext_vector_type(2))) float f32x2;

// ---- workspace layout (bytes) ----
#define OFF_SRE 0
#define OFF_SIM 131072
#define OFF_KY  262144
#define OFF_B   294912
#define OFF_C   5013504

__device__ __forceinline__ unsigned short f2bf(float f) {
    unsigned u = __float_as_uint(f);
    u += 0x7FFFu + ((u >> 16) & 1u);          // round-to-nearest-even
    return (unsigned short)(u >> 16);
}

__device__ __forceinline__ float bf2f(unsigned short v) {
    unsigned u = ((unsigned)v) << 16;
    return __uint_as_float(u);
}

__device__ __forceinline__ void lds_load16(const void* g, void* l) {
    __builtin_amdgcn_global_load_lds(
        (const __attribute__((address_space(1))) uint32_t*)(uintptr_t)g,
        (__attribute__((address_space(3))) uint32_t*)(uint32_t)(uintptr_t)l,
        16, 0, 0);
}

// ---------------- kernel 1: gather s + ky + build deduped Bt -------------------------
__global__ __launch_bounds__(256) void k_prep(const float* __restrict__ in,
                                              const float* __restrict__ xs,
                                              float* __restrict__ sRe,
                                              float* __restrict__ sIm,
                                              float* __restrict__ kyc,
                                              unsigned short* __restrict__ Bt) {
    int blk = blockIdx.x;
    if (blk < 128) {
        int t = blk * 256 + threadIdx.x;          // 32768
        int b = t >> 13, m = t & (M_MEAS - 1);
        float kx = xs[2 * m + 0], ky = xs[2 * m + 1];
        if (t < M_MEAS) kyc[t] = xs[2 * t + 1];
        float gx = (kx * (1.0f / 128.0f) + 1.0f) * 0.5f * 255.0f;
        float gy = (ky * (1.0f / 128.0f) + 1.0f) * 0.5f * 255.0f;
        float fx0 = floorf(gx), fy0 = floorf(gy);
        float wx1 = gx - fx0, wx0 = 1.0f - wx1;
        float wy1 = gy - fy0, wy0 = 1.0f - wy1;
        int x0 = (int)fx0, y0 = (int)fy0;
        float re = 0.0f, im = 0.0f;
#pragma unroll
        for (int dy = 0; dy < 2; ++dy) {
#pragma unroll
            for (int dx = 0; dx < 2; ++dx) {
                int xi = x0 + dx, yi = y0 + dy;
                bool v = (xi >= 0) && (xi < RES) && (yi >= 0) && (yi < RES);
                int xc = min(max(xi, 0), RES - 1);
                int yc = min(max(yi, 0), RES - 1);
                float w = (dx ? wx1 : wx0) * (dy ? wy1 : wy0) * (v ? 1.0f : 0.0f);
                const float* p = in + ((((size_t)b * RES + yc) * RES + xc) * 2);
                re += p[0] * w;
                im += p[1] * w;
            }
        }
        sRe[b * M_MEAS + m] = re;
        sIm[b * M_MEAS + m] = im;
    } else {
        int t = (blk - 128) * 256 + threadIdx.x;  // 294912 = 288*1024
        int cidx = t >> 10;
        int m0 = (t & 1023) * 8;
        bool isCos = cidx < SINOFF;
        int u = isCos ? cidx : (cidx - SINOFF);
        u16x8 v;
        if (u > 128) {
            v = (u16x8){0, 0, 0, 0, 0, 0, 0, 0};
        } else {
            float nn = (float)u;
#pragma unroll
            for (int j = 0; j < 8; ++j) {
                float kx = xs[2 * (m0 + j) + 0];
                float ur = kx * nn * (1.0f / 256.0f);
                ur -= rintf(ur);
                float th = ur * TWO_PI;
                v[j] = f2bf(isCos ? __cosf(th) : __sinf(th));
            }
        }
        *(u16x8*)(Bt + (size_t)cidx * KDIM + m0) = v;
    }
}

// ---------------- kernel 2: split-K GEMM, on-the-fly A -------------------------------
__global__ __launch_bounds__(256, 2) void k_gemm(const float* __restrict__ sReG,
                                                 const float* __restrict__ sImG,
                                                 const float* __restrict__ kyG,
                                                 const unsigned short* __restrict__ Bt,
                                                 unsigned short* __restrict__ Cp) {
    __shared__ __align__(16) unsigned short As[2][BM * BK];   // 2 x 16 KB
    __shared__ __align__(16) unsigned short Bs[2][BN * BK];   // 2 x 18 KB
    __shared__ __align__(16) float sbuf[3 * KCHUNK];          // 6 KB

    int bid = blockIdx.x;              // 512 = 2 col * 16 row * 16 split
    int tc = bid & 1, rest = bid >> 1;
    int tr = rest & 15, split = rest >> 4;
    int col0 = tc * BN;
    int kbase = split * KCHUNK;
    int yhalf = tr & 1, isIm = (tr >> 1) & 1, batch = tr >> 2;
    int tid = threadIdx.x;
    int w = tid >> 6, l = tid & 63;
    int lr = l & 15, lu = l >> 4;

    f32x4 acc[2][9] = {};

#define STAGE_B(buf, kt)                                                          \
    do {                                                                          \
        _Pragma("unroll")                                                         \
        for (int q = 0; q < 5; ++q) {                                             \
            int U = q * 256 + tid; if (U >= 1152) U -= 1152;                      \
            int r = U >> 3, u = U & 7;                                            \
            lds_load16(Bt + (size_t)(col0 + r) * KDIM + kbase + (kt) * BK         \
                          + ((u ^ (r & 7)) * 8),                                  \
                       &Bs[buf][U * 8]);                                          \
        }                                                                         \
    } while (0)

#define GEN_A(buf, kt)                                                            \
    do {                                                                          \
        int p = tid & 31, g = tid >> 5;                                           \
        int mi = (kt) * BK + p * 2;                                               \
        float2 kyp = *(const float2*)&sbuf[mi];                                   \
        float2 srp = *(const float2*)&sbuf[KCHUNK + mi];                          \
        float2 sip = *(const float2*)&sbuf[2 * KCHUNK + mi];                      \
        float n0 = (float)(yhalf * 128 + g * 16 - 128);                           \
        float c0, s0, c1, s1, cs0, ss0, cs1, ss1;                                 \
        { float u = kyp.x * n0 * (1.0f/256.0f); u -= rintf(u);                    \
          s0 = __sinf(u * TWO_PI); c0 = __cosf(u * TWO_PI); }                     \
        { float u = kyp.x * (1.0f/256.0f); u -= rintf(u);                         \
          ss0 = __sinf(u * TWO_PI); cs0 = __cosf(u * TWO_PI); }                   \
        { float u = kyp.y * n0 * (1.0f/256.0f); u -= rintf(u);                    \
          s1 = __sinf(u * TWO_PI); c1 = __cosf(u * TWO_PI); }                     \
        { float u = kyp.y * (1.0f/256.0f); u -= rintf(u);                         \
          ss1 = __sinf(u * TWO_PI); cs1 = __cosf(u * TWO_PI); }                   \
        _Pragma("unroll")                                                         \
        for (int j = 0; j < 16; ++j) {                                            \
            int r = g * 16 + j;                                                   \
            float v0 = isIm ? fmaf(srp.x, s0, sip.x * c0)                         \
                            : fmaf(srp.x, c0, -(sip.x * s0));                     \
            float v1 = isIm ? fmaf(srp.y, s1, sip.y * c1)                         \
                            : fmaf(srp.y, c1, -(sip.y * s1));                     \
            unsigned pk = (unsigned)f2bf(v0) | ((unsigned)f2bf(v1) << 16);        \
            *(unsigned*)&As[buf][r * 64 + (((p >> 2) ^ (r & 7)) * 8) + (p & 3) * 2] = pk; \
            float nc0 = fmaf(c0, cs0, -(s0 * ss0));                               \
            float ns0 = fmaf(s0, cs0,  (c0 * ss0));                               \
            c0 = nc0; s0 = ns0;                                                   \
            float nc1 = fmaf(c1, cs1, -(s1 * ss1));                               \
            float ns1 = fmaf(s1, cs1,  (c1 * ss1));                               \
            c1 = nc1; s1 = ns1;                                                   \
        }                                                                         \
    } while (0)

#pragma unroll
    for (int q = 0; q < 2; ++q) {
        int V = q * 256 + tid; if (V >= 384) V -= 384;
        int rg = V >> 7, idx = V & 127;
        const float* s = (rg == 0) ? kyG
                       : (rg == 1) ? (sReG + (size_t)batch * M_MEAS)
                                   : (sImG + (size_t)batch * M_MEAS);
        lds_load16(s + kbase + idx * 4, &sbuf[V * 4]);
    }
    STAGE_B(0, 0);
    asm volatile("s_waitcnt vmcnt(5)" ::: "memory");
    __builtin_amdgcn_s_barrier();
    GEN_A(0, 0);
    asm volatile("s_waitcnt vmcnt(0) lgkmcnt(0)" ::: "memory");
    __builtin_amdgcn_sched_barrier(0);
    __builtin_amdgcn_s_barrier();

    for (int t = 0; t < NT; ++t) {
        int cur = t & 1;
        if (t < NT - 1) {
            STAGE_B(cur ^ 1, t + 1);
            GEN_A(cur ^ 1, t + 1);
        }

        bf16x8 af[2][2], bfr[2][9];
#pragma unroll
        for (int ks = 0; ks < 2; ++ks) {
            int uu = ks * 4 + lu;
#pragma unroll
            for (int i = 0; i < 2; ++i) {
                int r = w * 32 + i * 16 + lr;
                af[ks][i] = *(const bf16x8*)&As[cur][r * 64 + ((uu ^ (r & 7)) * 8)];
            }
#pragma unroll
            for (int j = 0; j < 9; ++j) {
                int r = j * 16 + lr;
                bfr[ks][j] = *(const bf16x8*)&Bs[cur][r * 64 + ((uu ^ (r & 7)) * 8)];
            }
        }
        asm volatile("s_waitcnt lgkmcnt(0)" ::: "memory");
        __builtin_amdgcn_sched_barrier(0);
        __builtin_amdgcn_s_setprio(1);
#pragma unroll
        for (int ks = 0; ks < 2; ++ks)
#pragma unroll
            for (int i = 0; i < 2; ++i)
#pragma unroll
                for (int j = 0; j < 9; ++j)
                    acc[i][j] = __builtin_amdgcn_mfma_f32_16x16x32_bf16(af[ks][i], bfr[ks][j], acc[i][j], 0, 0, 0);
        __builtin_amdgcn_s_setprio(0);
        asm volatile("s_waitcnt vmcnt(0)" ::: "memory");
        __builtin_amdgcn_sched_barrier(0);
        __builtin_amdgcn_s_barrier();
    }
#undef STAGE_B
#undef GEN_A

    unsigned short* Cb = Cp + (size_t)split * ROWSC * NCOLS;
#pragma unroll
    for (int i = 0; i < 2; ++i) {
#pragma unroll
        for (int j = 0; j < 9; ++j) {
            int colg = col0 + j * 16 + lr;
#pragma unroll
            for (int v = 0; v < 4; ++v) {
                int rowg = tr * BM + w * 32 + i * 16 + lu * 4 + v;
                Cb[(size_t)rowg * NCOLS + colg] = f2bf(acc[i][j][v]);
            }
        }
    }
}

// ---------------- kernel 3: block-per-(b,y) cooperative split-K reduce ---------------
__global__ __launch_bounds__(256) void k_combine(const unsigned short* __restrict__ Cp,
                                                 float* __restrict__ out) {
    __shared__ float part[4 * 68 * 9];            // 9792 B
    int blk = blockIdx.x;
    int b = blk >> 8, y = blk & 255;
    int tid = threadIdx.x;
    int q = tid >> 6, un = tid & 63;

    size_t rRe = ((size_t)b * 512 + y) * NCOLS;
    size_t rIm = rRe + (size_t)256 * NCOLS;

#pragma unroll
    for (int rep = 0; rep < 2; ++rep) {
        int unit = un + rep * 64;
        if (rep == 1 && un >= 4) break;
        int seg = unit / 17, uidx = unit - seg * 17;
        size_t base = ((seg & 2) ? rIm : rRe) + ((seg & 1) ? SINOFF : 0) + uidx * 8;
        float a[8] = {};
#pragma unroll
        for (int s2 = 0; s2 < 4; ++s2) {
            const unsigned short* Cb = Cp + (size_t)(q * 4 + s2) * ROWSC * NCOLS;
            u16x8 v = *(const u16x8*)(Cb + base);
#pragma unroll
            for (int k = 0; k < 8; ++k) a[k] += bf2f(v[k]);
        }
#pragma unroll
        for (int k = 0; k < 8; ++k) part[(q * 68 + unit) * 9 + k] = a[k];
    }
    __syncthreads();

    if (tid < 68) {
#pragma unroll
        for (int k = 0; k < 8; ++k) {
            float s = part[(0 * 68 + tid) * 9 + k] + part[(1 * 68 + tid) * 9 + k]
                    + part[(2 * 68 + tid) * 9 + k] + part[(3 * 68 + tid) * 9 + k];
            part[tid * 9 + k] = s;
        }
    }
    __syncthreads();

    int x = tid;
    int n = x - 128;
    int u = (n < 0) ? -n : n;
    float sg = (n < 0) ? -1.0f : 1.0f;
    int ui = u >> 3, uk = u & 7;
    float cr = part[(0 * 17 + ui) * 9 + uk];
    float sr = part[(17 + ui) * 9 + uk];
    float ci = part[(34 + ui) * 9 + uk];
    float si = part[(51 + ui) * 9 + uk];
    float re = cr - sg * si;
    float im = sg * sr + ci;
    ((f32x2*)out)[(size_t)(b * 256 + y) * 256 + x] = (f32x2){re, im};
}

extern "C" void kernel_launch(void* const* d_in, const int* in_sizes, int n_in,
                              void* d_out, int out_size, void* d_ws, size_t ws_size,
                              hipStream_t stream) {
    const float* in = (const float*)d_in[0];
    const float* xs = (const float*)d_in[1];
    float* out = (float*)d_out;
    char* ws = (char*)d_ws;

    float* sRe = (float*)(ws + OFF_SRE);
    float* sIm = (float*)(ws + OFF_SIM);
    float* kyc = (float*)(ws + OFF_KY);
    unsigned short* Bt = (unsigned short*)(ws + OFF_B);
    unsigned short* Cp = (unsigned short*)(ws + OFF_C);

    k_prep   <<<128 + 1152, 256, 0, stream>>>(in, xs, sRe, sIm, kyc, Bt);
    k_gemm   <<<512,        256, 0, stream>>>(sRe, sIm, kyc, Bt, Cp);
    k_combine<<<1024,       256, 0, stream>>>(Cp, out);
}